// Round 1
// baseline (703.914 us; speedup 1.0000x reference)
//
#include <hip/hip_runtime.h>
#include <math.h>

// SSM classifier, restructured:
//  v = x @ (Bm@W_in)^T + Bm@b_in            (K=28 GEMM, bf16 out)
//  states = conv8(v, M_j=(A^T)^j)           (MFMA GEMM, K=2048, shifted-view A)
//  y = states @ C^T ; gelu ; LN ; write     (MFMA GEMM, fused epilogue)
//  logits = mean_t(normed) @ W_fc^T + b_fc

typedef __attribute__((ext_vector_type(8))) short short8;
typedef __attribute__((ext_vector_type(4))) float float4v;
typedef __attribute__((ext_vector_type(4))) unsigned int uint4v;
typedef unsigned short ushort_t;

// workspace layout (bytes)
#define WS_WB     0u          // 256x28 f32
#define WS_BB     28672u      // 256 f32
#define WS_MCAT   32768u      // 2048x256 bf16, B-swizzled
#define WS_CSWZ   1081344u    // 256x1024 bf16, B-swizzled
#define WS_P      1605632u    // 8 slots of 256x256 f32 (A^T powers)
#define WS_POOL   3702784u    // 64x1024 f32
#define WS_V      3964928u    // 65536x256 bf16
#define WS_S      37519360u   // 65536x256 bf16

__device__ __forceinline__ ushort_t f2bf(float f){
  unsigned int u = __builtin_bit_cast(unsigned int, f);
  u += 0x7fffu + ((u >> 16) & 1u);          // RNE
  return (ushort_t)(u >> 16);
}

// ---------------------------------------------------------------- prep
// blocks 0..255   : WB row s (= Bm@W_in row), bB[s]
// blocks 256..511 : Cswz  (B-swizzle of C^T for y GEMM)
// blocks 512..575 : Mcat j=0 (I) and j=1 (A^T), plus P[1] fp32
__global__ void k_prep(const float* __restrict__ Bm, const float* __restrict__ W_in,
                       const float* __restrict__ b_in, const float* __restrict__ A,
                       const float* __restrict__ C,
                       float* __restrict__ WB, float* __restrict__ bB,
                       ushort_t* __restrict__ Mcat, ushort_t* __restrict__ Cswz,
                       float* __restrict__ P){
  int blk = blockIdx.x, tid = threadIdx.x;
  if (blk < 256){
    __shared__ float red[29*257];
    int s = blk;
    float acc[29];
    #pragma unroll
    for (int i=0;i<29;i++) acc[i]=0.f;
    for (int d=tid; d<1024; d+=256){
      float bm = Bm[s*1024+d];
      const float* wr = W_in + d*28;
      #pragma unroll
      for (int i=0;i<28;i++) acc[i] += bm*wr[i];
      acc[28] += bm*b_in[d];
    }
    #pragma unroll
    for (int i=0;i<29;i++) red[i*257+tid] = acc[i];
    __syncthreads();
    if (tid < 29){
      float ssum = 0.f;
      for (int j=0;j<256;j++) ssum += red[tid*257+j];
      if (tid < 28) WB[s*28+tid] = ssum; else bB[s] = ssum;
    }
  } else if (blk < 512){
    int base = (blk-256)*1024;
    #pragma unroll
    for (int i=0;i<4;i++){
      int e = base + i*256 + tid;
      int k = e & 255, n = e >> 8;
      Cswz[(((k>>3)*1024 + n)<<3) + (k&7)] = f2bf(C[n*256 + k]);
    }
  } else {
    int base = (blk-512)*2048;
    #pragma unroll
    for (int i=0;i<8;i++){
      int e = base + i*256 + tid;
      int j = e >> 16;
      int k = (e >> 8) & 255, s = e & 255;
      float val = (j==0) ? ((k==s)?1.f:0.f) : A[s*256+k];
      int kg = j*256 + k;
      Mcat[(((kg>>3)*256 + s)<<3) + (kg&7)] = f2bf(val);
      if (j==1) P[65536 + k*256 + s] = val;
    }
  }
}

// ---------------------------------------------------------------- powers
// P[d] = P[a] @ P[b]  (powers of A^T commute); also writes bf16 into Mcat.
__global__ void k_powmul(float* __restrict__ P, ushort_t* __restrict__ Mcat,
                         int d0,int a0,int b0,int d1,int a1,int b1,int d2,int a2,int b2){
  int task = blockIdx.x >> 6, blk = blockIdx.x & 63, s = threadIdx.x;
  int dj,aj,bj;
  if (task==0){dj=d0;aj=a0;bj=b0;} else if (task==1){dj=d1;aj=a1;bj=b1;}
  else {dj=d2;aj=a2;bj=b2;}
  const float* Pa = P + aj*65536;
  const float* Pb = P + bj*65536;
  float acc[4] = {0.f,0.f,0.f,0.f};
  int k0 = blk*4;
  for (int p=0;p<256;p++){
    float bv = Pb[p*256 + s];
    #pragma unroll
    for (int kk=0;kk<4;kk++) acc[kk] += Pa[(k0+kk)*256 + p] * bv;
  }
  float* Pd = P + dj*65536;
  #pragma unroll
  for (int kk=0;kk<4;kk++){
    int k = k0+kk;
    Pd[k*256+s] = acc[kk];
    int kg = dj*256 + k;
    Mcat[(((kg>>3)*256 + s)<<3) + (kg&7)] = f2bf(acc[kk]);
  }
}

// ---------------------------------------------------------------- v = xs@WB^T + bB
__global__ void k_v(const float* __restrict__ xs, const float* __restrict__ WB,
                    const float* __restrict__ bB, ushort_t* __restrict__ V){
  int r0 = blockIdx.x * 64, tid = threadIdx.x;
  __shared__ float xsl[64*28];
  for (int i = tid; i < 64*28; i += 256) xsl[i] = xs[r0*28 + i];
  float wb[28];
  #pragma unroll
  for (int i=0;i<28;i++) wb[i] = WB[tid*28+i];
  float bb = bB[tid];
  __syncthreads();
  for (int rr=0; rr<64; rr++){
    float acc = bb;
    #pragma unroll
    for (int i=0;i<28;i++) acc += xsl[rr*28+i]*wb[i];
    V[(r0+rr)*256 + tid] = f2bf(acc);
  }
}

// ---------------------------------------------------------------- conv: states
// WG tile 128(t) x 256(s), K = 8 taps * 256 = 2048. A-matrix = shifted views of
// the V halo (135 rows) held once in LDS. B (Mcat) streamed from L2, pre-swizzled.
#define CR 264   // padded LDS row (bf16 elems): +8 breaks 512B stride conflicts
__global__ __launch_bounds__(256,2) void k_conv(const ushort_t* __restrict__ V,
                                                const ushort_t* __restrict__ Mcat,
                                                ushort_t* __restrict__ S){
  __shared__ ushort_t Vh[135*CR];
  int bid = blockIdx.x;
  int b = bid >> 3, t0 = (bid & 7) << 7;
  int tid = threadIdx.x;
  for (int idx = tid; idx < 135*32; idx += 256){
    int h = idx >> 5, c8 = (idx & 31) << 3;
    int t = t0 - 7 + h;
    uint4v val;
    if (t >= 0) val = *(const uint4v*)&V[(b*1024+t)*256 + c8];
    else        val = (uint4v){0u,0u,0u,0u};
    *(uint4v*)&Vh[h*CR + c8] = val;
  }
  __syncthreads();
  int w = tid >> 6, lane = tid & 63;
  int m16 = lane & 15, q = lane >> 4;
  int mh = (w >> 1) * 64, nh = (w & 1) * 128;
  float4v acc[4][8];
  #pragma unroll
  for (int mt=0;mt<4;mt++)
    #pragma unroll
    for (int nt=0;nt<8;nt++) acc[mt][nt] = (float4v){0.f,0.f,0.f,0.f};

  for (int kc=0; kc<64; kc++){
    int j = kc >> 3;                       // conv tap
    int col = ((kc & 7) << 5) + (q << 3);  // k within tap
    short8 a[4];
    #pragma unroll
    for (int mt=0;mt<4;mt++){
      int row = mh + mt*16 + m16 + 7 - j;  // shifted view
      a[mt] = *(const short8*)&Vh[row*CR + col];
    }
    int kq = (kc<<2) + q;
    short8 bf[8];
    #pragma unroll
    for (int nt=0;nt<8;nt++){
      int n = nh + nt*16 + m16;
      bf[nt] = *(const short8*)&Mcat[((kq*256 + n)<<3)];
    }
    #pragma unroll
    for (int mt=0;mt<4;mt++)
      #pragma unroll
      for (int nt=0;nt<8;nt++)
        acc[mt][nt] = __builtin_amdgcn_mfma_f32_16x16x32_bf16(a[mt], bf[nt], acc[mt][nt], 0,0,0);
  }
  __syncthreads();
  // stage bf16 tile in LDS, then coalesced 16B stores
  #pragma unroll
  for (int mt=0;mt<4;mt++)
    #pragma unroll
    for (int nt=0;nt<8;nt++)
      #pragma unroll
      for (int reg=0;reg<4;reg++){
        int row = mh + mt*16 + (q<<2) + reg;
        int s = nh + nt*16 + m16;
        Vh[row*CR + s] = f2bf(acc[mt][nt][reg]);
      }
  __syncthreads();
  for (int idx = tid; idx < 128*32; idx += 256){
    int row = idx >> 5, c8 = (idx & 31) << 3;
    *(uint4v*)&S[(b*1024 + t0 + row)*256 + c8] = *(const uint4v*)&Vh[row*CR + c8];
  }
}

// ---------------------------------------------------------------- y + gelu + LN + pool
// WG tile 32 rows x full D=1024. K=256. Fused epilogue, LDS-repacked fp32 stores.
__global__ __launch_bounds__(256,2) void k_y(const ushort_t* __restrict__ S,
                                             const ushort_t* __restrict__ Cswz,
                                             const float* __restrict__ gamma,
                                             const float* __restrict__ beta,
                                             float* __restrict__ outAct,
                                             float* __restrict__ pool){
  __shared__ union { ushort_t Sh[32*CR]; float Ost[16*1028]; } u;
  __shared__ float redS[32][4], redQ[32][4], muL[32], riL[32];
  int bid = blockIdx.x;
  int r0 = bid << 5;
  int bbatch = r0 >> 10;
  int tid = threadIdx.x;
  for (int idx = tid; idx < 32*32; idx += 256){
    int row = idx >> 5, c8 = (idx & 31) << 3;
    *(uint4v*)&u.Sh[row*CR + c8] = *(const uint4v*)&S[(r0+row)*256 + c8];
  }
  __syncthreads();
  int w = tid >> 6, lane = tid & 63;
  int m16 = lane & 15, q = lane >> 4;
  int ncol0 = w << 8;
  float4v acc[2][16];
  #pragma unroll
  for (int mt=0;mt<2;mt++)
    #pragma unroll
    for (int nt=0;nt<16;nt++) acc[mt][nt] = (float4v){0.f,0.f,0.f,0.f};

  for (int kc=0; kc<8; kc++){
    int col = (kc<<5) + (q<<3);
    short8 a0 = *(const short8*)&u.Sh[m16*CR + col];
    short8 a1 = *(const short8*)&u.Sh[(16+m16)*CR + col];
    int kq = (kc<<2) + q;
    #pragma unroll
    for (int half=0; half<2; half++){
      short8 bf[8];
      #pragma unroll
      for (int i=0;i<8;i++){
        int nt = half*8 + i;
        int n = ncol0 + nt*16 + m16;
        bf[i] = *(const short8*)&Cswz[((kq*1024 + n)<<3)];
      }
      #pragma unroll
      for (int i=0;i<8;i++){
        int nt = half*8 + i;
        acc[0][nt] = __builtin_amdgcn_mfma_f32_16x16x32_bf16(a0, bf[i], acc[0][nt], 0,0,0);
        acc[1][nt] = __builtin_amdgcn_mfma_f32_16x16x32_bf16(a1, bf[i], acc[1][nt], 0,0,0);
      }
    }
  }
  // exact GELU + row stats
  float s1[2][4], s2[2][4];
  #pragma unroll
  for (int mt=0;mt<2;mt++)
    #pragma unroll
    for (int r=0;r<4;r++){ s1[mt][r]=0.f; s2[mt][r]=0.f; }
  #pragma unroll
  for (int mt=0;mt<2;mt++)
    #pragma unroll
    for (int nt=0;nt<16;nt++)
      #pragma unroll
      for (int reg=0;reg<4;reg++){
        float y = acc[mt][nt][reg];
        float g = 0.5f*y*(1.f + erff(y*0.70710678f));
        acc[mt][nt][reg] = g;
        s1[mt][reg] += g;
        s2[mt][reg] += g*g;
      }
  #pragma unroll
  for (int mt=0;mt<2;mt++)
    #pragma unroll
    for (int reg=0;reg<4;reg++){
      float a_ = s1[mt][reg], b_ = s2[mt][reg];
      #pragma unroll
      for (int off=1; off<16; off<<=1){
        a_ += __shfl_xor(a_, off);
        b_ += __shfl_xor(b_, off);
      }
      if (m16 == 0){
        redS[mt*16 + (q<<2) + reg][w] = a_;
        redQ[mt*16 + (q<<2) + reg][w] = b_;
      }
    }
  __syncthreads();
  if (tid < 32){
    float sa = redS[tid][0]+redS[tid][1]+redS[tid][2]+redS[tid][3];
    float sb = redQ[tid][0]+redQ[tid][1]+redQ[tid][2]+redQ[tid][3];
    float mu = sa * (1.f/1024.f);
    float var = sb * (1.f/1024.f) - mu*mu;
    muL[tid] = mu;
    riL[tid] = 1.f / sqrtf(var + 1e-5f);
  }
  __syncthreads();
  float pp[16];
  #pragma unroll
  for (int nt=0;nt<16;nt++) pp[nt]=0.f;
  for (int mt=0; mt<2; mt++){
    if (mt) __syncthreads();
    #pragma unroll
    for (int nt=0;nt<16;nt++){
      int n = ncol0 + nt*16 + m16;
      float gm = gamma[n], bt = beta[n];
      #pragma unroll
      for (int reg=0;reg<4;reg++){
        int rloc = (q<<2) + reg;
        int row = mt*16 + rloc;
        float nv = (acc[mt][nt][reg] - muL[row]) * riL[row] * gm + bt;
        nv = (nv != nv) ? 0.f : fminf(fmaxf(nv, -1000000.f), 1000000.f);
        u.Ost[rloc*1028 + n] = nv;
        pp[nt] += nv;
      }
    }
    __syncthreads();
    for (int idx = tid; idx < 16*256; idx += 256){
      int row = idx >> 8, c4 = (idx & 255) << 2;
      *(float4v*)&outAct[(size_t)(r0 + mt*16 + row)*1024 + c4] =
          *(const float4v*)&u.Ost[row*1028 + c4];
    }
  }
  #pragma unroll
  for (int nt=0;nt<16;nt++){
    float v = pp[nt];
    v += __shfl_xor(v, 16);
    v += __shfl_xor(v, 32);
    if (q == 0) atomicAdd(&pool[bbatch*1024 + ncol0 + nt*16 + m16], v);
  }
}

// ---------------------------------------------------------------- logits
__global__ void k_logits(const float* __restrict__ pool, const float* __restrict__ Wfc,
                         const float* __restrict__ bfc, float* __restrict__ out0){
  int b = blockIdx.x, tid = threadIdx.x;
  float acc[10];
  #pragma unroll
  for (int c=0;c<10;c++) acc[c]=0.f;
  for (int d=tid; d<1024; d+=256){
    float p = pool[b*1024+d] * (1.f/1024.f);
    #pragma unroll
    for (int c=0;c<10;c++) acc[c] += p * Wfc[c*1024+d];
  }
  #pragma unroll
  for (int c=0;c<10;c++)
    #pragma unroll
    for (int off=1; off<64; off<<=1) acc[c] += __shfl_xor(acc[c], off);
  __shared__ float red[4][10];
  int w = tid >> 6, lane = tid & 63;
  if (lane == 0){
    #pragma unroll
    for (int c=0;c<10;c++) red[w][c] = acc[c];
  }
  __syncthreads();
  if (tid < 10) out0[b*10+tid] = bfc[tid] + red[0][tid]+red[1][tid]+red[2][tid]+red[3][tid];
}

// ---------------------------------------------------------------- launch
extern "C" void kernel_launch(void* const* d_in, const int* in_sizes, int n_in,
                              void* d_out, int out_size, void* d_ws, size_t ws_size,
                              hipStream_t stream) {
  (void)in_sizes; (void)n_in; (void)out_size; (void)ws_size;
  const float* x    = (const float*)d_in[0];
  const float* W_in = (const float*)d_in[1];
  const float* b_in = (const float*)d_in[2];
  const float* A    = (const float*)d_in[3];
  const float* Bm   = (const float*)d_in[4];
  const float* C    = (const float*)d_in[5];
  const float* gm   = (const float*)d_in[6];
  const float* bt   = (const float*)d_in[7];
  const float* Wfc  = (const float*)d_in[8];
  const float* bfc  = (const float*)d_in[9];

  char* ws = (char*)d_ws;
  float*    WB   = (float*)(ws + WS_WB);
  float*    bB   = (float*)(ws + WS_BB);
  ushort_t* Mcat = (ushort_t*)(ws + WS_MCAT);
  ushort_t* Cswz = (ushort_t*)(ws + WS_CSWZ);
  float*    P    = (float*)(ws + WS_P);
  float*    pool = (float*)(ws + WS_POOL);
  ushort_t* V    = (ushort_t*)(ws + WS_V);
  ushort_t* S    = (ushort_t*)(ws + WS_S);
  float*    out  = (float*)d_out;

  hipMemsetAsync(pool, 0, 64*1024*sizeof(float), stream);
  k_prep<<<576, 256, 0, stream>>>(Bm, W_in, b_in, A, C, WB, bB, Mcat, Cswz, P);
  // power doubling: M2=M1M1 ; M3=M1M2, M4=M2M2 ; M5=M1M4, M6=M2M4, M7=M3M4
  k_powmul<<<64, 256, 0, stream>>>(P, Mcat, 2,1,1, 0,0,0, 0,0,0);
  k_powmul<<<128,256, 0, stream>>>(P, Mcat, 3,1,2, 4,2,2, 0,0,0);
  k_powmul<<<192,256, 0, stream>>>(P, Mcat, 5,1,4, 6,2,4, 7,3,4);
  k_v<<<1024, 256, 0, stream>>>(x, WB, bB, V);
  k_conv<<<512, 256, 0, stream>>>(V, Mcat, S);
  k_y<<<2048, 256, 0, stream>>>(S, Cswz, gm, bt, out + 640, pool);
  k_logits<<<64, 256, 0, stream>>>(pool, Wfc, bfc, out);
}

// Round 2
// 563.312 us; speedup vs baseline: 1.2496x; 1.2496x over previous
//
#include <hip/hip_runtime.h>
#include <math.h>

// SSM classifier, restructured:
//  v = x @ (Bm@W_in)^T + Bm@b_in            (K=28 GEMM, bf16 out)
//  states = conv8(v, M_j=(A^T)^j)           (MFMA GEMM, K=2048, shifted-view A)
//  y = states @ C^T ; gelu ; LN ; write     (MFMA GEMM, fused epilogue)
//  logits = mean_t(normed) @ W_fc^T + b_fc
//
// R1 -> R2: k_y rewritten — no pool atomics (poolpart buffer aliasing dead V),
// no 64KB LDS store-staging (direct line-complete 4B stores), 512-thr blocks
// with 64-float accumulators (no spill risk at launch_bounds(512,2)).

typedef __attribute__((ext_vector_type(8))) short short8;
typedef __attribute__((ext_vector_type(4))) float float4v;
typedef __attribute__((ext_vector_type(4))) unsigned int uint4v;
typedef unsigned short ushort_t;

// workspace layout (bytes)
#define WS_WB     0u          // 256x28 f32
#define WS_BB     28672u      // 256 f32
#define WS_MCAT   32768u      // 2048x256 bf16, B-swizzled
#define WS_CSWZ   1081344u    // 256x1024 bf16, B-swizzled
#define WS_P      1605632u    // 8 slots of 256x256 f32 (A^T powers)
#define WS_V      3964928u    // 65536x256 bf16 (dead after k_conv; poolpart aliases it)
#define WS_S      37519360u   // 65536x256 bf16

__device__ __forceinline__ ushort_t f2bf(float f){
  unsigned int u = __builtin_bit_cast(unsigned int, f);
  u += 0x7fffu + ((u >> 16) & 1u);          // RNE
  return (ushort_t)(u >> 16);
}

// ---------------------------------------------------------------- prep
// blocks 0..255   : WB row s (= Bm@W_in row), bB[s]
// blocks 256..511 : Cswz  (B-swizzle of C^T for y GEMM)
// blocks 512..575 : Mcat j=0 (I) and j=1 (A^T), plus P[1] fp32
__global__ void k_prep(const float* __restrict__ Bm, const float* __restrict__ W_in,
                       const float* __restrict__ b_in, const float* __restrict__ A,
                       const float* __restrict__ C,
                       float* __restrict__ WB, float* __restrict__ bB,
                       ushort_t* __restrict__ Mcat, ushort_t* __restrict__ Cswz,
                       float* __restrict__ P){
  int blk = blockIdx.x, tid = threadIdx.x;
  if (blk < 256){
    __shared__ float red[29*257];
    int s = blk;
    float acc[29];
    #pragma unroll
    for (int i=0;i<29;i++) acc[i]=0.f;
    for (int d=tid; d<1024; d+=256){
      float bm = Bm[s*1024+d];
      const float* wr = W_in + d*28;
      #pragma unroll
      for (int i=0;i<28;i++) acc[i] += bm*wr[i];
      acc[28] += bm*b_in[d];
    }
    #pragma unroll
    for (int i=0;i<29;i++) red[i*257+tid] = acc[i];
    __syncthreads();
    if (tid < 29){
      float ssum = 0.f;
      for (int j=0;j<256;j++) ssum += red[tid*257+j];
      if (tid < 28) WB[s*28+tid] = ssum; else bB[s] = ssum;
    }
  } else if (blk < 512){
    int base = (blk-256)*1024;
    #pragma unroll
    for (int i=0;i<4;i++){
      int e = base + i*256 + tid;
      int k = e & 255, n = e >> 8;
      Cswz[(((k>>3)*1024 + n)<<3) + (k&7)] = f2bf(C[n*256 + k]);
    }
  } else {
    int base = (blk-512)*2048;
    #pragma unroll
    for (int i=0;i<8;i++){
      int e = base + i*256 + tid;
      int j = e >> 16;
      int k = (e >> 8) & 255, s = e & 255;
      float val = (j==0) ? ((k==s)?1.f:0.f) : A[s*256+k];
      int kg = j*256 + k;
      Mcat[(((kg>>3)*256 + s)<<3) + (kg&7)] = f2bf(val);
      if (j==1) P[65536 + k*256 + s] = val;
    }
  }
}

// ---------------------------------------------------------------- powers
// P[d] = P[a] @ P[b]  (powers of A^T commute); also writes bf16 into Mcat.
__global__ void k_powmul(float* __restrict__ P, ushort_t* __restrict__ Mcat,
                         int d0,int a0,int b0,int d1,int a1,int b1,int d2,int a2,int b2){
  int task = blockIdx.x >> 6, blk = blockIdx.x & 63, s = threadIdx.x;
  int dj,aj,bj;
  if (task==0){dj=d0;aj=a0;bj=b0;} else if (task==1){dj=d1;aj=a1;bj=b1;}
  else {dj=d2;aj=a2;bj=b2;}
  const float* Pa = P + aj*65536;
  const float* Pb = P + bj*65536;
  float acc[4] = {0.f,0.f,0.f,0.f};
  int k0 = blk*4;
  for (int p=0;p<256;p++){
    float bv = Pb[p*256 + s];
    #pragma unroll
    for (int kk=0;kk<4;kk++) acc[kk] += Pa[(k0+kk)*256 + p] * bv;
  }
  float* Pd = P + dj*65536;
  #pragma unroll
  for (int kk=0;kk<4;kk++){
    int k = k0+kk;
    Pd[k*256+s] = acc[kk];
    int kg = dj*256 + k;
    Mcat[(((kg>>3)*256 + s)<<3) + (kg&7)] = f2bf(acc[kk]);
  }
}

// ---------------------------------------------------------------- v = xs@WB^T + bB
__global__ void k_v(const float* __restrict__ xs, const float* __restrict__ WB,
                    const float* __restrict__ bB, ushort_t* __restrict__ V){
  int r0 = blockIdx.x * 64, tid = threadIdx.x;
  __shared__ float xsl[64*28];
  for (int i = tid; i < 64*28; i += 256) xsl[i] = xs[r0*28 + i];
  float wb[28];
  #pragma unroll
  for (int i=0;i<28;i++) wb[i] = WB[tid*28+i];
  float bb = bB[tid];
  __syncthreads();
  for (int rr=0; rr<64; rr++){
    float acc = bb;
    #pragma unroll
    for (int i=0;i<28;i++) acc += xsl[rr*28+i]*wb[i];
    V[(r0+rr)*256 + tid] = f2bf(acc);
  }
}

// ---------------------------------------------------------------- conv: states
// WG tile 128(t) x 256(s), K = 8 taps * 256 = 2048. A-matrix = shifted views of
// the V halo (135 rows) held once in LDS. B (Mcat) streamed from L2, pre-swizzled.
#define CR 264   // padded LDS row (bf16 elems): +8 breaks 512B stride conflicts
__global__ __launch_bounds__(256,2) void k_conv(const ushort_t* __restrict__ V,
                                                const ushort_t* __restrict__ Mcat,
                                                ushort_t* __restrict__ S){
  __shared__ ushort_t Vh[135*CR];
  int bid = blockIdx.x;
  int b = bid >> 3, t0 = (bid & 7) << 7;
  int tid = threadIdx.x;
  for (int idx = tid; idx < 135*32; idx += 256){
    int h = idx >> 5, c8 = (idx & 31) << 3;
    int t = t0 - 7 + h;
    uint4v val;
    if (t >= 0) val = *(const uint4v*)&V[(b*1024+t)*256 + c8];
    else        val = (uint4v){0u,0u,0u,0u};
    *(uint4v*)&Vh[h*CR + c8] = val;
  }
  __syncthreads();
  int w = tid >> 6, lane = tid & 63;
  int m16 = lane & 15, q = lane >> 4;
  int mh = (w >> 1) * 64, nh = (w & 1) * 128;
  float4v acc[4][8];
  #pragma unroll
  for (int mt=0;mt<4;mt++)
    #pragma unroll
    for (int nt=0;nt<8;nt++) acc[mt][nt] = (float4v){0.f,0.f,0.f,0.f};

  for (int kc=0; kc<64; kc++){
    int j = kc >> 3;                       // conv tap
    int col = ((kc & 7) << 5) + (q << 3);  // k within tap
    short8 a[4];
    #pragma unroll
    for (int mt=0;mt<4;mt++){
      int row = mh + mt*16 + m16 + 7 - j;  // shifted view
      a[mt] = *(const short8*)&Vh[row*CR + col];
    }
    int kq = (kc<<2) + q;
    short8 bf[8];
    #pragma unroll
    for (int nt=0;nt<8;nt++){
      int n = nh + nt*16 + m16;
      bf[nt] = *(const short8*)&Mcat[((kq*256 + n)<<3)];
    }
    #pragma unroll
    for (int mt=0;mt<4;mt++)
      #pragma unroll
      for (int nt=0;nt<8;nt++)
        acc[mt][nt] = __builtin_amdgcn_mfma_f32_16x16x32_bf16(a[mt], bf[nt], acc[mt][nt], 0,0,0);
  }
  __syncthreads();
  // stage bf16 tile in LDS, then coalesced 16B stores
  #pragma unroll
  for (int mt=0;mt<4;mt++)
    #pragma unroll
    for (int nt=0;nt<8;nt++)
      #pragma unroll
      for (int reg=0;reg<4;reg++){
        int row = mh + mt*16 + (q<<2) + reg;
        int s = nh + nt*16 + m16;
        Vh[row*CR + s] = f2bf(acc[mt][nt][reg]);
      }
  __syncthreads();
  for (int idx = tid; idx < 128*32; idx += 256){
    int row = idx >> 5, c8 = (idx & 31) << 3;
    *(uint4v*)&S[(b*1024 + t0 + row)*256 + c8] = *(const uint4v*)&Vh[row*CR + c8];
  }
}

// ---------------------------------------------------------------- y + gelu + LN + pool
// WG tile 32 rows x full D=1024, 512 threads (8 waves x 128-col slices). K=256.
// Direct line-complete stores from C-fragment layout; per-block pooled partials.
__global__ __launch_bounds__(512,2) void k_y(const ushort_t* __restrict__ S,
                                             const ushort_t* __restrict__ Cswz,
                                             const float* __restrict__ gamma,
                                             const float* __restrict__ beta,
                                             float* __restrict__ outAct,
                                             float* __restrict__ poolpart){
  __shared__ ushort_t Sh[32*CR];           // 16.9 KB
  __shared__ float redS[32][8], redQ[32][8], muL[32], riL[32];
  int bid = blockIdx.x;                     // 2048 blocks
  int r0 = bid << 5;
  int tid = threadIdx.x;
  for (int idx = tid; idx < 32*32; idx += 512){
    int row = idx >> 5, c8 = (idx & 31) << 3;
    *(uint4v*)&Sh[row*CR + c8] = *(const uint4v*)&S[(r0+row)*256 + c8];
  }
  __syncthreads();
  int w = tid >> 6, lane = tid & 63;        // w: 0..7
  int m16 = lane & 15, q = lane >> 4;
  int ncol0 = w << 7;                       // 128-col slice per wave
  float4v acc[2][8];
  #pragma unroll
  for (int mt=0;mt<2;mt++)
    #pragma unroll
    for (int nt=0;nt<8;nt++) acc[mt][nt] = (float4v){0.f,0.f,0.f,0.f};

  for (int kc=0; kc<8; kc++){
    int col = (kc<<5) + (q<<3);
    short8 a0 = *(const short8*)&Sh[m16*CR + col];
    short8 a1 = *(const short8*)&Sh[(16+m16)*CR + col];
    int kq = (kc<<2) + q;
    short8 bf[8];
    #pragma unroll
    for (int nt=0;nt<8;nt++){
      int n = ncol0 + nt*16 + m16;
      bf[nt] = *(const short8*)&Cswz[((kq*1024 + n)<<3)];
    }
    #pragma unroll
    for (int nt=0;nt<8;nt++){
      acc[0][nt] = __builtin_amdgcn_mfma_f32_16x16x32_bf16(a0, bf[nt], acc[0][nt], 0,0,0);
      acc[1][nt] = __builtin_amdgcn_mfma_f32_16x16x32_bf16(a1, bf[nt], acc[1][nt], 0,0,0);
    }
  }
  // exact GELU + row stats (per-wave partial over its 128 cols)
  float s1[2][4], s2[2][4];
  #pragma unroll
  for (int mt=0;mt<2;mt++)
    #pragma unroll
    for (int r=0;r<4;r++){ s1[mt][r]=0.f; s2[mt][r]=0.f; }
  #pragma unroll
  for (int mt=0;mt<2;mt++)
    #pragma unroll
    for (int nt=0;nt<8;nt++)
      #pragma unroll
      for (int reg=0;reg<4;reg++){
        float y = acc[mt][nt][reg];
        float g = 0.5f*y*(1.f + erff(y*0.70710678f));
        acc[mt][nt][reg] = g;
        s1[mt][reg] += g;
        s2[mt][reg] += g*g;
      }
  #pragma unroll
  for (int mt=0;mt<2;mt++)
    #pragma unroll
    for (int reg=0;reg<4;reg++){
      float a_ = s1[mt][reg], b_ = s2[mt][reg];
      #pragma unroll
      for (int off=1; off<16; off<<=1){
        a_ += __shfl_xor(a_, off);
        b_ += __shfl_xor(b_, off);
      }
      if (m16 == 0){
        redS[mt*16 + (q<<2) + reg][w] = a_;
        redQ[mt*16 + (q<<2) + reg][w] = b_;
      }
    }
  __syncthreads();
  if (tid < 32){
    float sa = 0.f, sb = 0.f;
    #pragma unroll
    for (int j=0;j<8;j++){ sa += redS[tid][j]; sb += redQ[tid][j]; }
    float mu = sa * (1.f/1024.f);
    float var = sb * (1.f/1024.f) - mu*mu;
    muL[tid] = mu;
    riL[tid] = 1.f / sqrtf(var + 1e-5f);
  }
  __syncthreads();
  // normalize + direct stores + pooled partials
  float pp[8];
  #pragma unroll
  for (int nt=0;nt<8;nt++) pp[nt]=0.f;
  #pragma unroll
  for (int mt=0; mt<2; mt++){
    #pragma unroll
    for (int nt=0;nt<8;nt++){
      int n = ncol0 + nt*16 + m16;
      float gm = gamma[n], bt = beta[n];
      #pragma unroll
      for (int reg=0;reg<4;reg++){
        int rloc = mt*16 + (q<<2) + reg;
        float nv = (acc[mt][nt][reg] - muL[rloc]) * riL[rloc] * gm + bt;
        nv = (nv != nv) ? 0.f : fminf(fmaxf(nv, -1000000.f), 1000000.f);
        outAct[(size_t)(r0 + rloc)*1024 + n] = nv;   // 16 lanes -> full 64B line
        pp[nt] += nv;
      }
    }
  }
  #pragma unroll
  for (int nt=0;nt<8;nt++){
    float v = pp[nt];
    v += __shfl_xor(v, 16);
    v += __shfl_xor(v, 32);
    if (q == 0) poolpart[(size_t)bid*1024 + ncol0 + nt*16 + m16] = v;
  }
}

// ---------------------------------------------------------------- logits
// batch b's rows live in k_y blocks b*32..b*32+31 (32 rows each).
__global__ void k_logits(const float* __restrict__ poolpart, const float* __restrict__ Wfc,
                         const float* __restrict__ bfc, float* __restrict__ out0){
  int b = blockIdx.x, tid = threadIdx.x;
  float acc[10];
  #pragma unroll
  for (int c=0;c<10;c++) acc[c]=0.f;
  for (int d=tid; d<1024; d+=256){
    float s = 0.f;
    #pragma unroll 4
    for (int p=0;p<32;p++) s += poolpart[(size_t)(b*32+p)*1024 + d];
    float pooled = s * (1.f/1024.f);
    #pragma unroll
    for (int c=0;c<10;c++) acc[c] += pooled * Wfc[c*1024+d];
  }
  #pragma unroll
  for (int c=0;c<10;c++)
    #pragma unroll
    for (int off=1; off<64; off<<=1) acc[c] += __shfl_xor(acc[c], off);
  __shared__ float red[4][10];
  int w = tid >> 6, lane = tid & 63;
  if (lane == 0){
    #pragma unroll
    for (int c=0;c<10;c++) red[w][c] = acc[c];
  }
  __syncthreads();
  if (tid < 10) out0[b*10+tid] = bfc[tid] + red[0][tid]+red[1][tid]+red[2][tid]+red[3][tid];
}

// ---------------------------------------------------------------- launch
extern "C" void kernel_launch(void* const* d_in, const int* in_sizes, int n_in,
                              void* d_out, int out_size, void* d_ws, size_t ws_size,
                              hipStream_t stream) {
  (void)in_sizes; (void)n_in; (void)out_size; (void)ws_size;
  const float* x    = (const float*)d_in[0];
  const float* W_in = (const float*)d_in[1];
  const float* b_in = (const float*)d_in[2];
  const float* A    = (const float*)d_in[3];
  const float* Bm   = (const float*)d_in[4];
  const float* C    = (const float*)d_in[5];
  const float* gm   = (const float*)d_in[6];
  const float* bt   = (const float*)d_in[7];
  const float* Wfc  = (const float*)d_in[8];
  const float* bfc  = (const float*)d_in[9];

  char* ws = (char*)d_ws;
  float*    WB   = (float*)(ws + WS_WB);
  float*    bB   = (float*)(ws + WS_BB);
  ushort_t* Mcat = (ushort_t*)(ws + WS_MCAT);
  ushort_t* Cswz = (ushort_t*)(ws + WS_CSWZ);
  float*    P    = (float*)(ws + WS_P);
  ushort_t* V    = (ushort_t*)(ws + WS_V);
  ushort_t* S    = (ushort_t*)(ws + WS_S);
  float*    poolpart = (float*)(ws + WS_V);   // aliases V (dead after k_conv)
  float*    out  = (float*)d_out;

  k_prep<<<576, 256, 0, stream>>>(Bm, W_in, b_in, A, C, WB, bB, Mcat, Cswz, P);
  // power doubling: M2=M1M1 ; M3=M1M2, M4=M2M2 ; M5=M1M4, M6=M2M4, M7=M3M4
  k_powmul<<<64, 256, 0, stream>>>(P, Mcat, 2,1,1, 0,0,0, 0,0,0);
  k_powmul<<<128,256, 0, stream>>>(P, Mcat, 3,1,2, 4,2,2, 0,0,0);
  k_powmul<<<192,256, 0, stream>>>(P, Mcat, 5,1,4, 6,2,4, 7,3,4);
  k_v<<<1024, 256, 0, stream>>>(x, WB, bB, V);
  k_conv<<<512, 256, 0, stream>>>(V, Mcat, S);
  k_y<<<2048, 512, 0, stream>>>(S, Cswz, gm, bt, out + 640, poolpart);
  k_logits<<<64, 256, 0, stream>>>(poolpart, Wfc, bfc, out);
}